// Round 1
// baseline (264.823 us; speedup 1.0000x reference)
//
#include <hip/hip_runtime.h>

#define S 4096
#define DM 512
#define NH 8
#define DHD 64
#define ALPHA 0.18033688011112042f /* 0.125 * log2(e): folds attn scale + exp2 base into Q */

using short8 = __attribute__((ext_vector_type(8))) short;  // 8 bf16 (4 VGPRs)
using f32x4  = __attribute__((ext_vector_type(4))) float;  // MFMA accumulator

__device__ __forceinline__ unsigned short f2bf(float f) {
  union { float f; unsigned int u; } v; v.f = f;
  unsigned int r = v.u + 0x7FFF + ((v.u >> 16) & 1);  // RNE
  return (unsigned short)(r >> 16);
}

__device__ __forceinline__ void async16(void* lds, const void* g) {
  // wave-uniform LDS base; HW writes base + lane*16
  __builtin_amdgcn_global_load_lds((const __attribute__((address_space(1))) void*)g,
                                   (__attribute__((address_space(3))) void*)lds, 16, 0, 0);
}

// ---------------- fp32 -> bf16 elementwise ----------------
__global__ void cvt_f32_bf16(const float* __restrict__ src, unsigned short* __restrict__ dst, int n) {
  int i = (blockIdx.x * 256 + threadIdx.x) * 4;
  if (i >= n) return;
  float4 v = *(const float4*)(src + i);
  uint2 o;
  o.x = (unsigned)f2bf(v.x) | ((unsigned)f2bf(v.y) << 16);
  o.y = (unsigned)f2bf(v.z) | ((unsigned)f2bf(v.w) << 16);
  *(uint2*)(dst + i) = o;
}

// ---------------- pack Wq/Wk/Wv -> Wcat^T [1536][512] bf16 (rows contiguous along d) ----------------
__global__ void pack_w(const float* __restrict__ Wq, const float* __restrict__ Wk,
                       const float* __restrict__ Wv, unsigned short* __restrict__ Wcat) {
  __shared__ float T[64][68];
  const int d0 = blockIdx.x * 64, h = blockIdx.y, t = blockIdx.z;
  const float* W = (t == 0 ? Wq : t == 1 ? Wk : Wv) + (size_t)h * DM * DHD;
  const int tid = threadIdx.x;
#pragma unroll
  for (int i = 0; i < 4; ++i) {
    int c = i * 256 + tid;           // 1024 chunks of 4 floats
    int r = c >> 4, u = c & 15;
    *(float4*)&T[r][u * 4] = *(const float4*)&W[(size_t)(d0 + r) * DHD + u * 4];
  }
  __syncthreads();
#pragma unroll
  for (int i = 0; i < 2; ++i) {
    int c = i * 256 + tid;           // 512 chunks of 8 bf16
    int dh = c >> 3, u = c & 7;
    unsigned short tmp[8];
#pragma unroll
    for (int j = 0; j < 8; ++j) tmp[j] = f2bf(T[u * 8 + j][dh]);
    *(uint4*)&Wcat[((size_t)(t * 512) + h * 64 + dh) * DM + d0 + u * 8] = *(uint4*)tmp;
  }
}

// ---------------- V [h][s][dh] -> Vt [h][dh][s] ----------------
__global__ void vtrans(const unsigned short* __restrict__ Vb, unsigned short* __restrict__ Vtb) {
  __shared__ unsigned short T[64][72];
  const int h = blockIdx.y, s0 = blockIdx.x * 64;
  const int tid = threadIdx.x;
#pragma unroll
  for (int i = 0; i < 2; ++i) {
    int c = i * 256 + tid;           // 512 chunks of 8
    int r = c >> 3, u = c & 7;
    *(uint4*)&T[r][u * 8] = *(const uint4*)&Vb[((size_t)h * S + s0 + r) * DHD + u * 8];
  }
  __syncthreads();
#pragma unroll
  for (int i = 0; i < 2; ++i) {
    int c = i * 256 + tid;
    int dh = c >> 3, u = c & 7;
    unsigned short tmp[8];
#pragma unroll
    for (int j = 0; j < 8; ++j) tmp[j] = T[u * 8 + j][dh];
    *(uint4*)&Vtb[((size_t)h * DHD + dh) * S + s0 + u * 8] = *(uint4*)tmp;
  }
}

// ---------------- 128x128 bt-GEMM (m97 structure), templated epilogue ----------------
// EPI=0: QKV (bias + Q-scale, scatter to Q/K/V bf16).  EPI=1: out-proj (bias, fp32 out).
template <int EPI>
__global__ void __launch_bounds__(256, 2)
gemm_bt(const unsigned short* __restrict__ A,   // [M][K] bf16
        const unsigned short* __restrict__ B,   // [N][K] bf16 (B^T rows)
        int K,
        const float* __restrict__ b0, const float* __restrict__ b1, const float* __restrict__ b2,
        unsigned short* __restrict__ Qb, unsigned short* __restrict__ Kb, unsigned short* __restrict__ Vb,
        float* __restrict__ outp) {
  __shared__ unsigned short As[128 * 32];
  __shared__ unsigned short Bs[128 * 32];
  const int tid = threadIdx.x;
  const int wid = tid >> 6, lane = tid & 63;
  const int lo = lane & 15, hi = lane >> 4;
  const int wr = wid >> 1, wc = wid & 1;
  const int m0 = blockIdx.x * 128, n0 = blockIdx.y * 128;
  f32x4 acc[4][4] = {};
  for (int k0 = 0; k0 < K; k0 += 32) {
    __syncthreads();  // protect LDS from overwrite while prev iter reads
#pragma unroll
    for (int i = 0; i < 2; ++i) {
      const int cb = (wid * 2 + i) * 64;
      const int c = cb + lane;
      const int r = c >> 2, u = c & 3;
      async16(&As[cb * 8], A + (size_t)(m0 + r) * K + k0 + u * 8);
      async16(&Bs[cb * 8], B + (size_t)(n0 + r) * K + k0 + u * 8);
    }
    __syncthreads();  // drains vmcnt -> LDS ready
    short8 af[4], bfr[4];
#pragma unroll
    for (int m = 0; m < 4; ++m) af[m] = *(const short8*)&As[(wr * 64 + m * 16 + lo) * 32 + hi * 8];
#pragma unroll
    for (int n = 0; n < 4; ++n) bfr[n] = *(const short8*)&Bs[(wc * 64 + n * 16 + lo) * 32 + hi * 8];
#pragma unroll
    for (int m = 0; m < 4; ++m)
#pragma unroll
      for (int n = 0; n < 4; ++n)
        acc[m][n] = __builtin_amdgcn_mfma_f32_16x16x32_bf16(af[m], bfr[n], acc[m][n], 0, 0, 0);
  }
#pragma unroll
  for (int mi = 0; mi < 4; ++mi)
#pragma unroll
    for (int ni = 0; ni < 4; ++ni)
#pragma unroll
      for (int r = 0; r < 4; ++r) {
        const int m = m0 + wr * 64 + mi * 16 + hi * 4 + r;
        const int n = n0 + wc * 64 + ni * 16 + lo;
        float v = acc[mi][ni][r];
        if (EPI == 0) {
          const int t = n >> 9, h = (n >> 6) & 7, dh = n & 63;
          v += (t == 0 ? b0 : t == 1 ? b1 : b2)[h * 64 + dh];
          if (t == 0) v *= ALPHA;  // fold softmax scale + log2e into Q
          unsigned short* dst = (t == 0 ? Qb : t == 1 ? Kb : Vb);
          dst[((size_t)h * S + m) * DHD + dh] = f2bf(v);
        } else {
          outp[(size_t)m * DM + n] = v + b0[n];
        }
      }
}

// ---------------- flash attention: 64 Q rows/block, 4 waves x 16 rows, KV tile 64 ----------------
__global__ void __launch_bounds__(256, 2)
attn_kernel(const unsigned short* __restrict__ Qb, const unsigned short* __restrict__ Kb,
            const unsigned short* __restrict__ Vtb, unsigned short* __restrict__ concat) {
  __shared__ unsigned short Ks[64 * 64];   // linear dest, XOR-swizzled content (pre-swizzled global src)
  __shared__ unsigned short Vs[64 * 64];   // same, rows = dh of V^T
  __shared__ unsigned short Ps[4][16 * 72];// per-wave P tile, +8 pad
  const int tid = threadIdx.x;
  const int wid = tid >> 6, lane = tid & 63;
  const int lo = lane & 15, hi = lane >> 4;
  const int h = blockIdx.y;
  const int q0 = blockIdx.x * 64;
  const unsigned short* Qh  = Qb  + (size_t)h * S * DHD;
  const unsigned short* Kh  = Kb  + (size_t)h * S * DHD;
  const unsigned short* Vth = Vtb + (size_t)h * DHD * S;
  short8 qf[2];
  const int qrow = q0 + wid * 16 + lo;
#pragma unroll
  for (int kf = 0; kf < 2; ++kf)
    qf[kf] = *(const short8*)&Qh[(size_t)qrow * DHD + kf * 32 + hi * 8];
  float m_r[4], l_r[4];
#pragma unroll
  for (int r = 0; r < 4; ++r) { m_r[r] = -__builtin_inff(); l_r[r] = 0.f; }
  f32x4 acc_o[4] = {};
  for (int kv0 = 0; kv0 < S; kv0 += 64) {
    __syncthreads();
#pragma unroll
    for (int i = 0; i < 2; ++i) {
      const int cb = (wid * 2 + i) * 64;
      const int c = cb + lane;
      const int r = c >> 3, up = c & 7;
      const int u = up ^ (r & 7);          // pre-swizzle the global source (m173 pattern)
      async16(&Ks[cb * 8], Kh  + (size_t)(kv0 + r) * DHD + u * 8);
      async16(&Vs[cb * 8], Vth + (size_t)r * S + kv0 + u * 8);
    }
    __syncthreads();
    // QK^T: rows=q (A=Q frags), cols=kv (B from K rows)
    f32x4 sc[4];
#pragma unroll
    for (int ct = 0; ct < 4; ++ct) {
      sc[ct] = (f32x4){0.f, 0.f, 0.f, 0.f};
#pragma unroll
      for (int kf = 0; kf < 2; ++kf) {
        const int r = ct * 16 + lo;
        const int u = kf * 4 + hi;
        const short8 kfr = *(const short8*)&Ks[r * 64 + (u ^ (r & 7)) * 8];
        sc[ct] = __builtin_amdgcn_mfma_f32_16x16x32_bf16(qf[kf], kfr, sc[ct], 0, 0, 0);
      }
    }
    // online softmax (base-2 logits; scale folded into Q)
    float pm[4];
#pragma unroll
    for (int r = 0; r < 4; ++r)
      pm[r] = fmaxf(fmaxf(sc[0][r], sc[1][r]), fmaxf(sc[2][r], sc[3][r]));
#pragma unroll
    for (int mm = 1; mm < 16; mm <<= 1)
#pragma unroll
      for (int r = 0; r < 4; ++r) pm[r] = fmaxf(pm[r], __shfl_xor(pm[r], mm));
    float sca[4], psum[4];
#pragma unroll
    for (int r = 0; r < 4; ++r) {
      const float mn = fmaxf(m_r[r], pm[r]);
      sca[r] = exp2f(m_r[r] - mn);
      m_r[r] = mn;
      psum[r] = 0.f;
    }
#pragma unroll
    for (int ct = 0; ct < 4; ++ct)
#pragma unroll
      for (int r = 0; r < 4; ++r) {
        const float p = exp2f(sc[ct][r] - m_r[r]);
        sc[ct][r] = p;
        psum[r] += p;
      }
#pragma unroll
    for (int mm = 1; mm < 16; mm <<= 1)
#pragma unroll
      for (int r = 0; r < 4; ++r) psum[r] += __shfl_xor(psum[r], mm);
#pragma unroll
    for (int r = 0; r < 4; ++r) l_r[r] = l_r[r] * sca[r] + psum[r];
#pragma unroll
    for (int dt = 0; dt < 4; ++dt)
#pragma unroll
      for (int r = 0; r < 4; ++r) acc_o[dt][r] *= sca[r];
    // P -> bf16 -> wave-private LDS (C-layout write, A-layout read)
    unsigned short* Pw = &Ps[wid][0];
#pragma unroll
    for (int ct = 0; ct < 4; ++ct)
#pragma unroll
      for (int r = 0; r < 4; ++r)
        Pw[(hi * 4 + r) * 72 + ct * 16 + lo] = f2bf(sc[ct][r]);
    asm volatile("" ::: "memory");  // forbid compiler reordering the cross-lane LDS read before the writes
    short8 pa[2];
#pragma unroll
    for (int kf = 0; kf < 2; ++kf)
      pa[kf] = *(const short8*)&Pw[lo * 72 + kf * 32 + hi * 8];
    // PV: rows=q (A=P), cols=dh (B from V^T rows)
#pragma unroll
    for (int dt = 0; dt < 4; ++dt)
#pragma unroll
      for (int kf = 0; kf < 2; ++kf) {
        const int r2 = dt * 16 + lo;
        const int u = kf * 4 + hi;
        const short8 vf = *(const short8*)&Vs[r2 * 64 + (u ^ (r2 & 7)) * 8];
        acc_o[dt] = __builtin_amdgcn_mfma_f32_16x16x32_bf16(pa[kf], vf, acc_o[dt], 0, 0, 0);
      }
  }
#pragma unroll
  for (int dt = 0; dt < 4; ++dt)
#pragma unroll
    for (int r = 0; r < 4; ++r) {
      const int row = q0 + wid * 16 + hi * 4 + r;
      const int col = h * DHD + dt * 16 + lo;
      concat[(size_t)row * DM + col] = f2bf(acc_o[dt][r] / l_r[r]);
    }
}

extern "C" void kernel_launch(void* const* d_in, const int* in_sizes, int n_in,
                              void* d_out, int out_size, void* d_ws, size_t ws_size,
                              hipStream_t stream) {
  const float* x  = (const float*)d_in[0];
  const float* Wq = (const float*)d_in[1];
  const float* Wk = (const float*)d_in[2];
  const float* Wv = (const float*)d_in[3];
  const float* bq = (const float*)d_in[4];
  const float* bk = (const float*)d_in[5];
  const float* bv = (const float*)d_in[6];
  const float* Wo = (const float*)d_in[7];
  const float* bo = (const float*)d_in[8];
  float* outp = (float*)d_out;
  char* ws = (char*)d_ws;
  // workspace carve (bytes)
  unsigned short* xb     = (unsigned short*)(ws + 0);          // 4 MB   x bf16 [4096][512]
  unsigned short* Wcat   = (unsigned short*)(ws + 4194304);    // 1.5 MB W^T   [1536][512]
  unsigned short* Wob    = (unsigned short*)(ws + 5767168);    // 0.5 MB Wo    [512][512]
  unsigned short* Qbuf   = (unsigned short*)(ws + 6291456);    // 4 MB   [8][4096][64]
  unsigned short* Kbuf   = (unsigned short*)(ws + 10485760);   // 4 MB
  unsigned short* Vbuf   = (unsigned short*)(ws + 14680064);   // 4 MB
  unsigned short* Vtbuf  = (unsigned short*)(ws + 18874368);   // 4 MB   [8][64][4096]
  unsigned short* concat = (unsigned short*)(ws + 23068672);   // 4 MB   [4096][512]

  cvt_f32_bf16<<<(S * DM) / 1024, 256, 0, stream>>>(x, xb, S * DM);
  cvt_f32_bf16<<<(DM * DM) / 1024, 256, 0, stream>>>(Wo, Wob, DM * DM);
  pack_w<<<dim3(8, NH, 3), 256, 0, stream>>>(Wq, Wk, Wv, Wcat);
  gemm_bt<0><<<dim3(S / 128, 1536 / 128), 256, 0, stream>>>(xb, Wcat, DM, bq, bk, bv,
                                                            Qbuf, Kbuf, Vbuf, nullptr);
  vtrans<<<dim3(S / 64, NH), 256, 0, stream>>>(Vbuf, Vtbuf);
  attn_kernel<<<dim3(S / 64, NH), 256, 0, stream>>>(Qbuf, Kbuf, Vtbuf, concat);
  gemm_bt<1><<<dim3(S / 128, DM / 128), 256, 0, stream>>>(concat, Wob, DM, bo, nullptr, nullptr,
                                                          nullptr, nullptr, nullptr, outp);
}

// Round 2
// 205.431 us; speedup vs baseline: 1.2891x; 1.2891x over previous
//
#include <hip/hip_runtime.h>

#define S 4096
#define DM 512
#define NH 8
#define DHD 64
#define ALPHA 0.18033688011112042f /* 0.125 * log2(e): folds attn scale + exp2 base into Q */

using short8 = __attribute__((ext_vector_type(8))) short;  // 8 bf16 (4 VGPRs)
using f32x4  = __attribute__((ext_vector_type(4))) float;  // MFMA accumulator

__device__ __forceinline__ unsigned short f2bf(float f) {
  union { float f; unsigned int u; } v; v.f = f;
  unsigned int r = v.u + 0x7FFF + ((v.u >> 16) & 1);  // RNE
  return (unsigned short)(r >> 16);
}

__device__ __forceinline__ unsigned int cvt_pk_bf16(float a, float b) {
  unsigned int r;
  asm("v_cvt_pk_bf16_f32 %0, %1, %2" : "=v"(r) : "v"(a), "v"(b));
  return r;  // low16 = bf16(a), high16 = bf16(b)
}

__device__ __forceinline__ void async16(void* lds, const void* g) {
  // wave-uniform LDS base; HW writes base + lane*16
  __builtin_amdgcn_global_load_lds((const __attribute__((address_space(1))) void*)g,
                                   (__attribute__((address_space(3))) void*)lds, 16, 0, 0);
}

// ---------------- fp32 -> bf16 elementwise ----------------
__global__ void cvt_f32_bf16(const float* __restrict__ src, unsigned short* __restrict__ dst, int n) {
  int i = (blockIdx.x * 256 + threadIdx.x) * 4;
  if (i >= n) return;
  float4 v = *(const float4*)(src + i);
  uint2 o;
  o.x = (unsigned)f2bf(v.x) | ((unsigned)f2bf(v.y) << 16);
  o.y = (unsigned)f2bf(v.z) | ((unsigned)f2bf(v.w) << 16);
  *(uint2*)(dst + i) = o;
}

// ---------------- pack Wq/Wk/Wv -> Wcat^T [1536][512] bf16 (rows contiguous along d) ----------------
__global__ void pack_w(const float* __restrict__ Wq, const float* __restrict__ Wk,
                       const float* __restrict__ Wv, unsigned short* __restrict__ Wcat) {
  __shared__ float T[64][68];
  const int d0 = blockIdx.x * 64, h = blockIdx.y, t = blockIdx.z;
  const float* W = (t == 0 ? Wq : t == 1 ? Wk : Wv) + (size_t)h * DM * DHD;
  const int tid = threadIdx.x;
#pragma unroll
  for (int i = 0; i < 4; ++i) {
    int c = i * 256 + tid;           // 1024 chunks of 4 floats
    int r = c >> 4, u = c & 15;
    *(float4*)&T[r][u * 4] = *(const float4*)&W[(size_t)(d0 + r) * DHD + u * 4];
  }
  __syncthreads();
#pragma unroll
  for (int i = 0; i < 2; ++i) {
    int c = i * 256 + tid;           // 512 chunks of 8 bf16
    int dh = c >> 3, u = c & 7;
    unsigned short tmp[8];
#pragma unroll
    for (int j = 0; j < 8; ++j) tmp[j] = f2bf(T[u * 8 + j][dh]);
    *(uint4*)&Wcat[((size_t)(t * 512) + h * 64 + dh) * DM + d0 + u * 8] = *(uint4*)tmp;
  }
}

// ---------------- V [h][s][dh] -> Vt [h][dh][s] ----------------
__global__ void vtrans(const unsigned short* __restrict__ Vb, unsigned short* __restrict__ Vtb) {
  __shared__ unsigned short T[64][72];
  const int h = blockIdx.y, s0 = blockIdx.x * 64;
  const int tid = threadIdx.x;
#pragma unroll
  for (int i = 0; i < 2; ++i) {
    int c = i * 256 + tid;           // 512 chunks of 8
    int r = c >> 3, u = c & 7;
    *(uint4*)&T[r][u * 8] = *(const uint4*)&Vb[((size_t)h * S + s0 + r) * DHD + u * 8];
  }
  __syncthreads();
#pragma unroll
  for (int i = 0; i < 2; ++i) {
    int c = i * 256 + tid;
    int dh = c >> 3, u = c & 7;
    unsigned short tmp[8];
#pragma unroll
    for (int j = 0; j < 8; ++j) tmp[j] = T[u * 8 + j][dh];
    *(uint4*)&Vtb[((size_t)h * DHD + dh) * S + s0 + u * 8] = *(uint4*)tmp;
  }
}

// ---------------- 128x128 bt-GEMM (m97 structure), templated epilogue ----------------
// EPI=0: QKV (bias + Q-scale, scatter to Q/K/V bf16).  EPI=1: out-proj (bias, fp32 out).
template <int EPI>
__global__ void __launch_bounds__(256, 2)
gemm_bt(const unsigned short* __restrict__ A,   // [M][K] bf16
        const unsigned short* __restrict__ B,   // [N][K] bf16 (B^T rows)
        int K,
        const float* __restrict__ b0, const float* __restrict__ b1, const float* __restrict__ b2,
        unsigned short* __restrict__ Qb, unsigned short* __restrict__ Kb, unsigned short* __restrict__ Vb,
        float* __restrict__ outp) {
  __shared__ unsigned short As[128 * 32];
  __shared__ unsigned short Bs[128 * 32];
  const int tid = threadIdx.x;
  const int wid = tid >> 6, lane = tid & 63;
  const int lo = lane & 15, hi = lane >> 4;
  const int wr = wid >> 1, wc = wid & 1;
  const int m0 = blockIdx.x * 128, n0 = blockIdx.y * 128;
  f32x4 acc[4][4] = {};
  for (int k0 = 0; k0 < K; k0 += 32) {
    __syncthreads();  // protect LDS from overwrite while prev iter reads
#pragma unroll
    for (int i = 0; i < 2; ++i) {
      const int cb = (wid * 2 + i) * 64;
      const int c = cb + lane;
      const int r = c >> 2, u = c & 3;
      async16(&As[cb * 8], A + (size_t)(m0 + r) * K + k0 + u * 8);
      async16(&Bs[cb * 8], B + (size_t)(n0 + r) * K + k0 + u * 8);
    }
    __syncthreads();  // drains vmcnt -> LDS ready
    short8 af[4], bfr[4];
#pragma unroll
    for (int m = 0; m < 4; ++m) af[m] = *(const short8*)&As[(wr * 64 + m * 16 + lo) * 32 + hi * 8];
#pragma unroll
    for (int n = 0; n < 4; ++n) bfr[n] = *(const short8*)&Bs[(wc * 64 + n * 16 + lo) * 32 + hi * 8];
#pragma unroll
    for (int m = 0; m < 4; ++m)
#pragma unroll
      for (int n = 0; n < 4; ++n)
        acc[m][n] = __builtin_amdgcn_mfma_f32_16x16x32_bf16(af[m], bfr[n], acc[m][n], 0, 0, 0);
  }
#pragma unroll
  for (int mi = 0; mi < 4; ++mi)
#pragma unroll
    for (int ni = 0; ni < 4; ++ni)
#pragma unroll
      for (int r = 0; r < 4; ++r) {
        const int m = m0 + wr * 64 + mi * 16 + hi * 4 + r;
        const int n = n0 + wc * 64 + ni * 16 + lo;
        float v = acc[mi][ni][r];
        if (EPI == 0) {
          const int t = n >> 9, h = (n >> 6) & 7, dh = n & 63;
          v += (t == 0 ? b0 : t == 1 ? b1 : b2)[h * 64 + dh];
          if (t == 0) v *= ALPHA;  // fold softmax scale + log2e into Q
          unsigned short* dst = (t == 0 ? Qb : t == 1 ? Kb : Vb);
          dst[((size_t)h * S + m) * DHD + dh] = f2bf(v);
        } else {
          outp[(size_t)m * DM + n] = v + b0[n];
        }
      }
}

// ---------------- flash attention, swapped-operand structure ----------------
// 64 Q rows/block, 4 waves x 16 rows. KV tile 64, double-buffered staging (1 barrier/iter).
// QK^T computed as mfma(K,Q) -> lane owns ONE q-row (q=lane&15); softmax reduce is
// 15 in-lane ops + 2 shfl_xor. PV computed as mfma(V^T, P^T) -> output col=q stays
// lane-local, so m/l rescale needs no cross-lane traffic.
__global__ void __launch_bounds__(256, 2)
attn_kernel(const unsigned short* __restrict__ Qb, const unsigned short* __restrict__ Kb,
            const unsigned short* __restrict__ Vtb, unsigned short* __restrict__ concat) {
  __shared__ unsigned short Ks[2][64 * 64];  // linear dest, XOR-swizzled content
  __shared__ unsigned short Vs[2][64 * 64];  // rows = dh of V^T
  __shared__ unsigned short Ps[4][16 * 72];  // per-wave P tile [q=16][kv=64], stride 72
  const int tid = threadIdx.x;
  const int wid = tid >> 6, lane = tid & 63;
  const int lo = lane & 15, hi = lane >> 4;
  const int h = blockIdx.y;
  const int q0 = blockIdx.x * 64;
  const unsigned short* Qh  = Qb  + (size_t)h * S * DHD;
  const unsigned short* Kh  = Kb  + (size_t)h * S * DHD;
  const unsigned short* Vth = Vtb + (size_t)h * DHD * S;
  // Q as B-operand: col=lo -> q-row, k over dh
  const int qrow = q0 + wid * 16 + lo;
  short8 qf[2];
#pragma unroll
  for (int kf = 0; kf < 2; ++kf)
    qf[kf] = *(const short8*)&Qh[(size_t)qrow * DHD + kf * 32 + hi * 8];

  float m_r = -__builtin_inff(), l_r = 0.f;
  f32x4 acc[4] = {};  // acc[dt]: row = dh = dt*16 + hi*4 + r, col = q = lo

  // stage KV tile kv0 into buffer b (pre-swizzled global source, linear LDS dest)
  auto stage = [&](int b, int kv0) {
#pragma unroll
    for (int i = 0; i < 2; ++i) {
      const int cb = (wid * 2 + i) * 64;
      const int c = cb + lane;
      const int r = c >> 3, up = c & 7;
      const int u = up ^ (r & 7);
      async16(&Ks[b][cb * 8], Kh  + (size_t)(kv0 + r) * DHD + u * 8);
      async16(&Vs[b][cb * 8], Vth + (size_t)r * S + kv0 + u * 8);
    }
  };

  stage(0, 0);
  __syncthreads();  // drains vmcnt(0): tile 0 resident
  int cur = 0;
  for (int kv0 = 0; kv0 < S; kv0 += 64) {
    if (kv0 + 64 < S) stage(cur ^ 1, kv0 + 64);  // prefetch next tile under compute
    // --- QK^T (swapped): sc[ct] rows = kv = ct*16 + hi*4 + r, col = q = lo ---
    f32x4 sc[4];
#pragma unroll
    for (int ct = 0; ct < 4; ++ct) {
      sc[ct] = (f32x4){0.f, 0.f, 0.f, 0.f};
#pragma unroll
      for (int kf = 0; kf < 2; ++kf) {
        const int r = ct * 16 + lo;
        const int u = kf * 4 + hi;
        const short8 kfr = *(const short8*)&Ks[cur][r * 64 + (u ^ (r & 7)) * 8];
        sc[ct] = __builtin_amdgcn_mfma_f32_16x16x32_bf16(kfr, qf[kf], sc[ct], 0, 0, 0);
      }
    }
    // --- online softmax: all 16 scores for q=lo live in this lane ---
    float pm0 = fmaxf(fmaxf(sc[0][0], sc[0][1]), fmaxf(sc[0][2], sc[0][3]));
    float pm1 = fmaxf(fmaxf(sc[1][0], sc[1][1]), fmaxf(sc[1][2], sc[1][3]));
    float pm2 = fmaxf(fmaxf(sc[2][0], sc[2][1]), fmaxf(sc[2][2], sc[2][3]));
    float pm3 = fmaxf(fmaxf(sc[3][0], sc[3][1]), fmaxf(sc[3][2], sc[3][3]));
    float pm = fmaxf(fmaxf(pm0, pm1), fmaxf(pm2, pm3));
    pm = fmaxf(pm, __shfl_xor(pm, 16));
    pm = fmaxf(pm, __shfl_xor(pm, 32));
    const float mn = fmaxf(m_r, pm);
    const float sca = exp2f(m_r - mn);
    m_r = mn;
    float ps = 0.f;
#pragma unroll
    for (int ct = 0; ct < 4; ++ct)
#pragma unroll
      for (int r = 0; r < 4; ++r) {
        const float p = exp2f(sc[ct][r] - mn);
        sc[ct][r] = p;
        ps += p;
      }
    ps += __shfl_xor(ps, 16);
    ps += __shfl_xor(ps, 32);
    l_r = l_r * sca + ps;
#pragma unroll
    for (int dt = 0; dt < 4; ++dt)
#pragma unroll
      for (int r = 0; r < 4; ++r) acc[dt][r] *= sca;
    // --- P -> bf16 -> per-wave LDS [q][kv] (uniform-spread b64 writes) ---
    unsigned short* Pw = &Ps[wid][0];
#pragma unroll
    for (int ct = 0; ct < 4; ++ct) {
      uint2 w;
      w.x = cvt_pk_bf16(sc[ct][0], sc[ct][1]);  // kv = ct*16+hi*4 +0,+1
      w.y = cvt_pk_bf16(sc[ct][2], sc[ct][3]);  //             +2,+3
      *(uint2*)&Pw[lo * 72 + ct * 16 + hi * 4] = w;
    }
    asm volatile("" ::: "memory");  // keep the cross-lane LDS read after the writes
    short8 pb[2];
#pragma unroll
    for (int kc = 0; kc < 2; ++kc)
      pb[kc] = *(const short8*)&Pw[lo * 72 + kc * 32 + hi * 8];
    // --- PV (swapped): A = V^T rows=dh, B = P^T cols=q ---
#pragma unroll
    for (int dt = 0; dt < 4; ++dt)
#pragma unroll
      for (int kc = 0; kc < 2; ++kc) {
        const int r2 = dt * 16 + lo;
        const int u = kc * 4 + hi;
        const short8 vf = *(const short8*)&Vs[cur][r2 * 64 + (u ^ (r2 & 7)) * 8];
        acc[dt] = __builtin_amdgcn_mfma_f32_16x16x32_bf16(vf, pb[kc], acc[dt], 0, 0, 0);
      }
    __syncthreads();  // all waves done reading `cur`; prefetched loads drained
    cur ^= 1;
  }
  // epilogue: ctx[q][dh] = acc^T / l; q = qrow is lane-local
  const float inv_l = 1.f / l_r;
#pragma unroll
  for (int dt = 0; dt < 4; ++dt) {
    unsigned short tmp[4];
#pragma unroll
    for (int r = 0; r < 4; ++r) tmp[r] = f2bf(acc[dt][r] * inv_l);
    *(uint2*)&concat[(size_t)qrow * DM + h * DHD + dt * 16 + hi * 4] = *(uint2*)tmp;
  }
}

extern "C" void kernel_launch(void* const* d_in, const int* in_sizes, int n_in,
                              void* d_out, int out_size, void* d_ws, size_t ws_size,
                              hipStream_t stream) {
  const float* x  = (const float*)d_in[0];
  const float* Wq = (const float*)d_in[1];
  const float* Wk = (const float*)d_in[2];
  const float* Wv = (const float*)d_in[3];
  const float* bq = (const float*)d_in[4];
  const float* bk = (const float*)d_in[5];
  const float* bv = (const float*)d_in[6];
  const float* Wo = (const float*)d_in[7];
  const float* bo = (const float*)d_in[8];
  float* outp = (float*)d_out;
  char* ws = (char*)d_ws;
  // workspace carve (bytes)
  unsigned short* xb     = (unsigned short*)(ws + 0);          // 4 MB   x bf16 [4096][512]
  unsigned short* Wcat   = (unsigned short*)(ws + 4194304);    // 1.5 MB W^T   [1536][512]
  unsigned short* Wob    = (unsigned short*)(ws + 5767168);    // 0.5 MB Wo    [512][512]
  unsigned short* Qbuf   = (unsigned short*)(ws + 6291456);    // 4 MB   [8][4096][64]
  unsigned short* Kbuf   = (unsigned short*)(ws + 10485760);   // 4 MB
  unsigned short* Vbuf   = (unsigned short*)(ws + 14680064);   // 4 MB
  unsigned short* Vtbuf  = (unsigned short*)(ws + 18874368);   // 4 MB   [8][64][4096]
  unsigned short* concat = (unsigned short*)(ws + 23068672);   // 4 MB   [4096][512]

  cvt_f32_bf16<<<(S * DM) / 1024, 256, 0, stream>>>(x, xb, S * DM);
  cvt_f32_bf16<<<(DM * DM) / 1024, 256, 0, stream>>>(Wo, Wob, DM * DM);
  pack_w<<<dim3(8, NH, 3), 256, 0, stream>>>(Wq, Wk, Wv, Wcat);
  gemm_bt<0><<<dim3(S / 128, 1536 / 128), 256, 0, stream>>>(xb, Wcat, DM, bq, bk, bv,
                                                            Qbuf, Kbuf, Vbuf, nullptr);
  vtrans<<<dim3(S / 64, NH), 256, 0, stream>>>(Vbuf, Vtbuf);
  attn_kernel<<<dim3(S / 64, NH), 256, 0, stream>>>(Qbuf, Kbuf, Vtbuf, concat);
  gemm_bt<1><<<dim3(S / 128, DM / 128), 256, 0, stream>>>(concat, Wob, DM, bo, nullptr, nullptr,
                                                          nullptr, nullptr, nullptr, outp);
}

// Round 3
// 184.601 us; speedup vs baseline: 1.4346x; 1.1128x over previous
//
#include <hip/hip_runtime.h>

#define S 4096
#define DM 512
#define NH 8
#define DHD 64
#define KVSPLIT 2
#define KVLEN (S / KVSPLIT)
#define ALPHA 0.18033688011112042f /* 0.125 * log2(e): folds attn scale + exp2 base into Q */

using short8 = __attribute__((ext_vector_type(8))) short;  // 8 bf16 (4 VGPRs)
using f32x4  = __attribute__((ext_vector_type(4))) float;  // MFMA accumulator

__device__ __forceinline__ unsigned short f2bf(float f) {
  union { float f; unsigned int u; } v; v.f = f;
  unsigned int r = v.u + 0x7FFF + ((v.u >> 16) & 1);  // RNE
  return (unsigned short)(r >> 16);
}

__device__ __forceinline__ float bf2f(unsigned short u) {
  union { unsigned int u; float f; } v; v.u = (unsigned)u << 16;
  return v.f;
}

__device__ __forceinline__ unsigned int cvt_pk_bf16(float a, float b) {
  unsigned int r;
  asm("v_cvt_pk_bf16_f32 %0, %1, %2" : "=v"(r) : "v"(a), "v"(b));
  return r;  // low16 = bf16(a), high16 = bf16(b)
}

__device__ __forceinline__ void async16(void* lds, const void* g) {
  // wave-uniform LDS base; HW writes base + lane*16
  __builtin_amdgcn_global_load_lds((const __attribute__((address_space(1))) void*)g,
                                   (__attribute__((address_space(3))) void*)lds, 16, 0, 0);
}

// ---------------- fp32 -> bf16: x and Wo in one launch ----------------
__global__ void cvt2_f32_bf16(const float* __restrict__ a, unsigned short* __restrict__ da, int na,
                              const float* __restrict__ b, unsigned short* __restrict__ db, int nb) {
  int i = (blockIdx.x * 256 + threadIdx.x) * 4;
  const float* src; unsigned short* dst;
  if (i < na) { src = a + i; dst = da + i; }
  else { int j = i - na; if (j >= nb) return; src = b + j; dst = db + j; }
  float4 v = *(const float4*)src;
  uint2 o;
  o.x = (unsigned)f2bf(v.x) | ((unsigned)f2bf(v.y) << 16);
  o.y = (unsigned)f2bf(v.z) | ((unsigned)f2bf(v.w) << 16);
  *(uint2*)dst = o;
}

// ---------------- pack Wq/Wk/Wv -> Wcat^T [1536][512] bf16 (rows contiguous along d) ----------------
__global__ void pack_w(const float* __restrict__ Wq, const float* __restrict__ Wk,
                       const float* __restrict__ Wv, unsigned short* __restrict__ Wcat) {
  __shared__ float T[64][68];
  const int d0 = blockIdx.x * 64, h = blockIdx.y, t = blockIdx.z;
  const float* W = (t == 0 ? Wq : t == 1 ? Wk : Wv) + (size_t)h * DM * DHD;
  const int tid = threadIdx.x;
#pragma unroll
  for (int i = 0; i < 4; ++i) {
    int c = i * 256 + tid;
    int r = c >> 4, u = c & 15;
    *(float4*)&T[r][u * 4] = *(const float4*)&W[(size_t)(d0 + r) * DHD + u * 4];
  }
  __syncthreads();
#pragma unroll
  for (int i = 0; i < 2; ++i) {
    int c = i * 256 + tid;
    int dh = c >> 3, u = c & 7;
    unsigned short tmp[8];
#pragma unroll
    for (int j = 0; j < 8; ++j) tmp[j] = f2bf(T[u * 8 + j][dh]);
    *(uint4*)&Wcat[((size_t)(t * 512) + h * 64 + dh) * DM + d0 + u * 8] = *(uint4*)tmp;
  }
}

// ---------------- 128x128 bt-GEMM (m97 structure), templated epilogue ----------------
// EPI=0: QKV (bias + Q-scale; Q,K row-major, V written TRANSPOSED to Vt).  EPI=1: out-proj.
template <int EPI>
__global__ void __launch_bounds__(256, 2)
gemm_bt(const unsigned short* __restrict__ A,   // [M][K] bf16
        const unsigned short* __restrict__ B,   // [N][K] bf16 (B^T rows)
        int K,
        const float* __restrict__ b0, const float* __restrict__ b1, const float* __restrict__ b2,
        unsigned short* __restrict__ Qb, unsigned short* __restrict__ Kb, unsigned short* __restrict__ Vtb,
        float* __restrict__ outp) {
  __shared__ unsigned short As[128 * 32];
  __shared__ unsigned short Bs[128 * 32];
  const int tid = threadIdx.x;
  const int wid = tid >> 6, lane = tid & 63;
  const int lo = lane & 15, hi = lane >> 4;
  const int wr = wid >> 1, wc = wid & 1;
  const int m0 = blockIdx.x * 128, n0 = blockIdx.y * 128;
  f32x4 acc[4][4] = {};
  for (int k0 = 0; k0 < K; k0 += 32) {
    __syncthreads();
#pragma unroll
    for (int i = 0; i < 2; ++i) {
      const int cb = (wid * 2 + i) * 64;
      const int c = cb + lane;
      const int r = c >> 2, u = c & 3;
      async16(&As[cb * 8], A + (size_t)(m0 + r) * K + k0 + u * 8);
      async16(&Bs[cb * 8], B + (size_t)(n0 + r) * K + k0 + u * 8);
    }
    __syncthreads();
    short8 af[4], bfr[4];
#pragma unroll
    for (int m = 0; m < 4; ++m) af[m] = *(const short8*)&As[(wr * 64 + m * 16 + lo) * 32 + hi * 8];
#pragma unroll
    for (int n = 0; n < 4; ++n) bfr[n] = *(const short8*)&Bs[(wc * 64 + n * 16 + lo) * 32 + hi * 8];
#pragma unroll
    for (int m = 0; m < 4; ++m)
#pragma unroll
      for (int n = 0; n < 4; ++n)
        acc[m][n] = __builtin_amdgcn_mfma_f32_16x16x32_bf16(af[m], bfr[n], acc[m][n], 0, 0, 0);
  }
#pragma unroll
  for (int mi = 0; mi < 4; ++mi)
#pragma unroll
    for (int ni = 0; ni < 4; ++ni) {
      const int n = n0 + wc * 64 + ni * 16 + lo;
      const int mbase = m0 + wr * 64 + mi * 16 + hi * 4;
      if (EPI == 0) {
        const int t = n >> 9, h = (n >> 6) & 7, dh = n & 63;  // t,h wave-uniform per (mi,ni)
        const float bias = (t == 0 ? b0 : t == 1 ? b1 : b2)[h * 64 + dh];
        if (t == 2) {
          // V^T: 4 consecutive s positions on row dh -> one 8B store
          unsigned short tmp[4];
#pragma unroll
          for (int r = 0; r < 4; ++r) tmp[r] = f2bf(acc[mi][ni][r] + bias);
          *(uint2*)&Vtb[((size_t)h * DHD + dh) * S + mbase] = *(uint2*)tmp;
        } else {
          unsigned short* dst = (t == 0 ? Qb : Kb);
#pragma unroll
          for (int r = 0; r < 4; ++r) {
            float v = acc[mi][ni][r] + bias;
            if (t == 0) v *= ALPHA;
            dst[((size_t)h * S + mbase + r) * DHD + dh] = f2bf(v);
          }
        }
      } else {
#pragma unroll
        for (int r = 0; r < 4; ++r)
          outp[(size_t)(mbase + r) * DM + n] = acc[mi][ni][r] + b0[n];
      }
    }
}

// ---------------- flash attention, swapped operands + KV-split 2 ----------------
// grid (S/64, NH, KVSPLIT). 4 waves x 16 q-rows. LDS = 2*16K (K,V dbuf) + 8K (P swz) = 40960
// -> 4 blocks/CU (16 waves/CU). Lane owns one q-row (q=lane&15): softmax in-lane + 2 shfl.
// Defer-max (T13, THR=8) skips rescale on ~95% of tiles. Partials (m,l fp32; acc bf16) merged later.
__global__ void __launch_bounds__(256, 4)
attn_kernel(const unsigned short* __restrict__ Qb, const unsigned short* __restrict__ Kb,
            const unsigned short* __restrict__ Vtb, unsigned short* __restrict__ accP,
            float2* __restrict__ lmP) {
  __shared__ unsigned short Ks[2][64 * 64];  // linear dest, XOR-swizzled content
  __shared__ unsigned short Vs[2][64 * 64];
  __shared__ unsigned short Ps[4][16 * 64];  // per-wave P tile, XOR-swizzled (T2), no pad
  const int tid = threadIdx.x;
  const int wid = tid >> 6, lane = tid & 63;
  const int lo = lane & 15, hi = lane >> 4;
  const int h = blockIdx.y;
  const int q0 = blockIdx.x * 64;
  const int sp = blockIdx.z;
  const int kvbase = sp * KVLEN;
  const unsigned short* Qh  = Qb  + (size_t)h * S * DHD;
  const unsigned short* Kh  = Kb  + (size_t)h * S * DHD;
  const unsigned short* Vth = Vtb + (size_t)h * DHD * S;
  const int qrow = q0 + wid * 16 + lo;
  short8 qf[2];
#pragma unroll
  for (int kf = 0; kf < 2; ++kf)
    qf[kf] = *(const short8*)&Qh[(size_t)qrow * DHD + kf * 32 + hi * 8];

  float m_r = -__builtin_inff(), l_r = 0.f;
  f32x4 acc[4] = {};  // acc[dt]: row = dh = dt*16 + hi*4 + r, col = q = lo

  auto stage = [&](int b, int kv0) {
#pragma unroll
    for (int i = 0; i < 2; ++i) {
      const int cb = (wid * 2 + i) * 64;
      const int c = cb + lane;
      const int r = c >> 3, up = c & 7;
      const int u = up ^ (r & 7);          // pre-swizzle global source (m173)
      async16(&Ks[b][cb * 8], Kh  + (size_t)(kv0 + r) * DHD + u * 8);
      async16(&Vs[b][cb * 8], Vth + (size_t)r * S + kv0 + u * 8);
    }
  };

  stage(0, kvbase);
  __syncthreads();
  int cur = 0;
  for (int kv0 = kvbase; kv0 < kvbase + KVLEN; kv0 += 64) {
    if (kv0 + 64 < kvbase + KVLEN) stage(cur ^ 1, kv0 + 64);
    // --- QK^T (swapped): sc[ct] rows = kv = ct*16 + hi*4 + r, col = q = lo ---
    f32x4 sc[4];
    __builtin_amdgcn_s_setprio(1);
#pragma unroll
    for (int ct = 0; ct < 4; ++ct) {
      sc[ct] = (f32x4){0.f, 0.f, 0.f, 0.f};
#pragma unroll
      for (int kf = 0; kf < 2; ++kf) {
        const int r = ct * 16 + lo;
        const int u = kf * 4 + hi;
        const short8 kfr = *(const short8*)&Ks[cur][r * 64 + (u ^ (r & 7)) * 8];
        sc[ct] = __builtin_amdgcn_mfma_f32_16x16x32_bf16(kfr, qf[kf], sc[ct], 0, 0, 0);
      }
    }
    __builtin_amdgcn_s_setprio(0);
    // --- online softmax, all 16 scores for q=lo in-lane ---
    float pm = fmaxf(fmaxf(fmaxf(sc[0][0], sc[0][1]), fmaxf(sc[0][2], sc[0][3])),
                     fmaxf(fmaxf(sc[1][0], sc[1][1]), fmaxf(sc[1][2], sc[1][3])));
    pm = fmaxf(pm, fmaxf(fmaxf(fmaxf(sc[2][0], sc[2][1]), fmaxf(sc[2][2], sc[2][3])),
                         fmaxf(fmaxf(sc[3][0], sc[3][1]), fmaxf(sc[3][2], sc[3][3]))));
    pm = fmaxf(pm, __shfl_xor(pm, 16));
    pm = fmaxf(pm, __shfl_xor(pm, 32));
    if (__any(pm > m_r + 8.f)) {        // defer-max: rescale only when headroom exceeded
      const float mn = fmaxf(m_r, pm);
      const float sca = exp2f(m_r - mn);
      m_r = mn;
      l_r *= sca;
#pragma unroll
      for (int dt = 0; dt < 4; ++dt)
#pragma unroll
        for (int r = 0; r < 4; ++r) acc[dt][r] *= sca;
    }
    float ps = 0.f;
#pragma unroll
    for (int ct = 0; ct < 4; ++ct)
#pragma unroll
      for (int r = 0; r < 4; ++r) {
        const float p = exp2f(sc[ct][r] - m_r);  // bounded by 2^8
        sc[ct][r] = p;
        ps += p;
      }
    ps += __shfl_xor(ps, 16);
    ps += __shfl_xor(ps, 32);
    l_r += ps;
    // --- P -> bf16 -> per-wave XOR-swizzled LDS (write C-layout, read B-frag layout) ---
    unsigned short* Pw = &Ps[wid][0];
    const int swz = (lo & 7) << 3;  // XOR in shorts (16B in bytes)
#pragma unroll
    for (int ct = 0; ct < 4; ++ct) {
      uint2 w;
      w.x = cvt_pk_bf16(sc[ct][0], sc[ct][1]);
      w.y = cvt_pk_bf16(sc[ct][2], sc[ct][3]);
      *(uint2*)&Pw[lo * 64 + ((ct * 16 + hi * 4) ^ swz)] = w;
    }
    asm volatile("" ::: "memory");
    short8 pb[2];
#pragma unroll
    for (int kc = 0; kc < 2; ++kc)
      pb[kc] = *(const short8*)&Pw[lo * 64 + ((kc * 32 + hi * 8) ^ swz)];
    // --- PV (swapped): A = V^T rows=dh, B = P^T cols=q ---
    __builtin_amdgcn_s_setprio(1);
#pragma unroll
    for (int dt = 0; dt < 4; ++dt)
#pragma unroll
      for (int kc = 0; kc < 2; ++kc) {
        const int r2 = dt * 16 + lo;
        const int u = kc * 4 + hi;
        const short8 vf = *(const short8*)&Vs[cur][r2 * 64 + (u ^ (r2 & 7)) * 8];
        acc[dt] = __builtin_amdgcn_mfma_f32_16x16x32_bf16(vf, pb[kc], acc[dt], 0, 0, 0);
      }
    __builtin_amdgcn_s_setprio(0);
    __syncthreads();
    cur ^= 1;
  }
  // partial epilogue: raw acc (bf16) + (m,l)
  const size_t prow = (size_t)(sp * NH + h) * S + qrow;
#pragma unroll
  for (int dt = 0; dt < 4; ++dt) {
    unsigned short tmp[4];
#pragma unroll
    for (int r = 0; r < 4; ++r) tmp[r] = f2bf(acc[dt][r]);
    *(uint2*)&accP[prow * 64 + dt * 16 + hi * 4] = *(uint2*)tmp;
  }
  if (hi == 0) lmP[prow] = make_float2(m_r, l_r);
}

// ---------------- merge the KV-split partials -> concat bf16 ----------------
__global__ void merge_kernel(const unsigned short* __restrict__ accP, const float2* __restrict__ lmP,
                             unsigned short* __restrict__ concat) {
  const int c = blockIdx.x * 256 + threadIdx.x;  // one 8-wide dh chunk
  const int row = c >> 3;                        // h*S + q
  const int h = row >> 12, q = row & (S - 1);
  const int dh0 = (c & 7) * 8;
  const float2 lm0 = lmP[row];
  const float2 lm1 = lmP[NH * S + row];
  const float M = fmaxf(lm0.x, lm1.x);
  float w0 = exp2f(lm0.x - M), w1 = exp2f(lm1.x - M);
  const float inv = 1.f / (lm0.y * w0 + lm1.y * w1);
  w0 *= inv; w1 *= inv;
  const short8 v0 = *(const short8*)&accP[(size_t)row * 64 + dh0];
  const short8 v1 = *(const short8*)&accP[((size_t)NH * S + row) * 64 + dh0];
  unsigned short out[8];
#pragma unroll
  for (int j = 0; j < 8; ++j)
    out[j] = f2bf(bf2f((unsigned short)v0[j]) * w0 + bf2f((unsigned short)v1[j]) * w1);
  *(uint4*)&concat[(size_t)q * DM + h * DHD + dh0] = *(uint4*)out;
}

extern "C" void kernel_launch(void* const* d_in, const int* in_sizes, int n_in,
                              void* d_out, int out_size, void* d_ws, size_t ws_size,
                              hipStream_t stream) {
  const float* x  = (const float*)d_in[0];
  const float* Wq = (const float*)d_in[1];
  const float* Wk = (const float*)d_in[2];
  const float* Wv = (const float*)d_in[3];
  const float* bq = (const float*)d_in[4];
  const float* bk = (const float*)d_in[5];
  const float* bv = (const float*)d_in[6];
  const float* Wo = (const float*)d_in[7];
  const float* bo = (const float*)d_in[8];
  float* outp = (float*)d_out;
  char* ws = (char*)d_ws;
  // workspace carve (bytes); accP overlaps xb/Wcat (dead after gemm<0>)
  unsigned short* Qbuf   = (unsigned short*)(ws + 0);          // 4 MB [8][4096][64]
  unsigned short* Kbuf   = (unsigned short*)(ws + 4194304);    // 4 MB
  unsigned short* Vtbuf  = (unsigned short*)(ws + 8388608);    // 4 MB [8][64][4096]
  unsigned short* concat = (unsigned short*)(ws + 12582912);   // 4 MB [4096][512]
  unsigned short* Wob    = (unsigned short*)(ws + 16777216);   // 0.5 MB
  float2*         lmP    = (float2*)(ws + 17301504);           // 0.5 MB [2][8][4096]
  unsigned short* xb     = (unsigned short*)(ws + 17825792);   // 4 MB (dead after gemm<0>)
  unsigned short* Wcat   = (unsigned short*)(ws + 22020096);   // 1.5 MB (dead after gemm<0>)
  unsigned short* accP   = (unsigned short*)(ws + 17825792);   // 8 MB bf16 [2][8][4096][64]

  cvt2_f32_bf16<<<(S * DM + DM * DM) / 1024, 256, 0, stream>>>(x, xb, S * DM, Wo, Wob, DM * DM);
  pack_w<<<dim3(8, NH, 3), 256, 0, stream>>>(Wq, Wk, Wv, Wcat);
  gemm_bt<0><<<dim3(S / 128, 1536 / 128), 256, 0, stream>>>(xb, Wcat, DM, bq, bk, bv,
                                                            Qbuf, Kbuf, Vtbuf, nullptr);
  attn_kernel<<<dim3(S / 64, NH, KVSPLIT), 256, 0, stream>>>(Qbuf, Kbuf, Vtbuf, accP, lmP);
  merge_kernel<<<(NH * S * 8) / 256, 256, 0, stream>>>(accP, lmP, concat);
  gemm_bt<1><<<dim3(S / 128, DM / 128), 256, 0, stream>>>(concat, Wob, DM, bo, nullptr, nullptr,
                                                          nullptr, nullptr, nullptr, outp);
}

// Round 5
// 174.071 us; speedup vs baseline: 1.5214x; 1.0605x over previous
//
#include <hip/hip_runtime.h>

#define S 4096
#define DM 512
#define NH 8
#define DHD 64
#define KVSPLIT 2
#define KVLEN (S / KVSPLIT)
#define ALPHA 0.18033688011112042f /* 0.125 * log2(e): folds attn scale + exp2 base into Q */

using short8 = __attribute__((ext_vector_type(8))) short;  // 8 bf16 (4 VGPRs)
using f32x4  = __attribute__((ext_vector_type(4))) float;
using f32x16 = __attribute__((ext_vector_type(16))) float; // 32x32 MFMA accumulator

__device__ __forceinline__ unsigned short f2bf(float f) {
  union { float f; unsigned int u; } v; v.f = f;
  unsigned int r = v.u + 0x7FFF + ((v.u >> 16) & 1);  // RNE
  return (unsigned short)(r >> 16);
}

__device__ __forceinline__ float bf2f(unsigned short u) {
  union { unsigned int u; float f; } v; v.u = (unsigned)u << 16;
  return v.f;
}

__device__ __forceinline__ unsigned int cvt_pk_bf16(float a, float b) {
  unsigned int r;
  asm("v_cvt_pk_bf16_f32 %0, %1, %2" : "=v"(r) : "v"(a), "v"(b));
  return r;  // low16 = bf16(a), high16 = bf16(b)
}

// v_permlane32_swap_b32 semantics (HK-recipe-consistent direction):
//   new vdst[lane+32] = old vsrc[lane]   (vdst.row1 <- vsrc.row0)
//   new vsrc[lane]    = old vdst[lane+32](vsrc.row0 <- vdst.row1)
//   vdst.row0, vsrc.row1 unchanged.
__device__ __forceinline__ void permswap(unsigned int& d, unsigned int& s) {
  asm("v_permlane32_swap_b32 %0, %1" : "+v"(d), "+v"(s));
}

__device__ __forceinline__ void async16(void* lds, const void* g) {
  // wave-uniform LDS base; HW writes base + lane*16
  __builtin_amdgcn_global_load_lds((const __attribute__((address_space(1))) void*)g,
                                   (__attribute__((address_space(3))) void*)lds, 16, 0, 0);
}

// ---------------- prep: fp32->bf16 (x, Wo) + Wq/Wk/Wv -> Wcat^T, one dispatch ----------------
#define NCVT ((S * DM + DM * DM) / 1024)  // 2304 blocks
__global__ void prep(const float* __restrict__ x, unsigned short* __restrict__ xb,
                     const float* __restrict__ Wo, unsigned short* __restrict__ Wob,
                     const float* __restrict__ Wq, const float* __restrict__ Wk,
                     const float* __restrict__ Wv, unsigned short* __restrict__ Wcat) {
  __shared__ float T[64][68];
  const int tid = threadIdx.x;
  if (blockIdx.x < NCVT) {  // block-uniform branch; no barrier in this path
    int i = (blockIdx.x * 256 + tid) * 4;
    const float* src; unsigned short* dst;
    if (i < S * DM) { src = x + i; dst = xb + i; }
    else { int j = i - S * DM; src = Wo + j; dst = Wob + j; }
    float4 v = *(const float4*)src;
    uint2 o;
    o.x = (unsigned)f2bf(v.x) | ((unsigned)f2bf(v.y) << 16);
    o.y = (unsigned)f2bf(v.z) | ((unsigned)f2bf(v.w) << 16);
    *(uint2*)dst = o;
    return;
  }
  const int bid = blockIdx.x - NCVT;
  const int d0 = (bid & 7) * 64, h = (bid >> 3) & 7, t = bid >> 6;
  const float* W = (t == 0 ? Wq : t == 1 ? Wk : Wv) + (size_t)h * DM * DHD;
#pragma unroll
  for (int i = 0; i < 4; ++i) {
    int c = i * 256 + tid;
    int r = c >> 4, u = c & 15;
    *(float4*)&T[r][u * 4] = *(const float4*)&W[(size_t)(d0 + r) * DHD + u * 4];
  }
  __syncthreads();
#pragma unroll
  for (int i = 0; i < 2; ++i) {
    int c = i * 256 + tid;
    int dh = c >> 3, u = c & 7;
    unsigned short tmp[8];
#pragma unroll
    for (int j = 0; j < 8; ++j) tmp[j] = f2bf(T[u * 8 + j][dh]);
    *(uint4*)&Wcat[((size_t)(t * 512) + h * 64 + dh) * DM + d0 + u * 8] = *(uint4*)tmp;
  }
}

// ---------------- 128x64-tile bt-GEMM, templated epilogue ----------------
// EPI=0: QKV (bias + Q-scale; Q,K row-major, V transposed to Vt). EPI=1: out-proj fp32+bias.
template <int EPI>
__global__ void __launch_bounds__(256, 4)
gemm_bt(const unsigned short* __restrict__ A,   // [M][K] bf16
        const unsigned short* __restrict__ B,   // [N][K] bf16 (B^T rows)
        int K,
        const float* __restrict__ b0, const float* __restrict__ b1, const float* __restrict__ b2,
        unsigned short* __restrict__ Qb, unsigned short* __restrict__ Kb, unsigned short* __restrict__ Vtb,
        float* __restrict__ outp) {
  __shared__ unsigned short As[128 * 32];
  __shared__ unsigned short Bs[64 * 32];
  const int tid = threadIdx.x;
  const int wid = tid >> 6, lane = tid & 63;
  const int lo = lane & 15, hi = lane >> 4;
  const int wr = wid >> 1, wc = wid & 1;
  const int m0 = blockIdx.x * 128, n0 = blockIdx.y * 64;
  f32x4 acc[4][2] = {};
  for (int k0 = 0; k0 < K; k0 += 32) {
    __syncthreads();
#pragma unroll
    for (int i = 0; i < 2; ++i) {
      const int cb = (wid * 2 + i) * 64;
      const int c = cb + lane, r = c >> 2, u = c & 3;
      async16(&As[cb * 8], A + (size_t)(m0 + r) * K + k0 + u * 8);
    }
    {
      const int cb = wid * 64;
      const int c = cb + lane, r = c >> 2, u = c & 3;
      async16(&Bs[cb * 8], B + (size_t)(n0 + r) * K + k0 + u * 8);
    }
    __syncthreads();
    short8 af[4], bfr[2];
#pragma unroll
    for (int m = 0; m < 4; ++m) af[m] = *(const short8*)&As[(wr * 64 + m * 16 + lo) * 32 + hi * 8];
#pragma unroll
    for (int n = 0; n < 2; ++n) bfr[n] = *(const short8*)&Bs[(wc * 32 + n * 16 + lo) * 32 + hi * 8];
#pragma unroll
    for (int m = 0; m < 4; ++m)
#pragma unroll
      for (int n = 0; n < 2; ++n)
        acc[m][n] = __builtin_amdgcn_mfma_f32_16x16x32_bf16(af[m], bfr[n], acc[m][n], 0, 0, 0);
  }
#pragma unroll
  for (int mi = 0; mi < 4; ++mi)
#pragma unroll
    for (int ni = 0; ni < 2; ++ni) {
      const int n = n0 + wc * 32 + ni * 16 + lo;
      const int mbase = m0 + wr * 64 + mi * 16 + hi * 4;
      if (EPI == 0) {
        const int t = n >> 9, h = (n >> 6) & 7, dh = n & 63;  // wave-uniform t,h per (mi,ni)
        const float bias = (t == 0 ? b0 : t == 1 ? b1 : b2)[h * 64 + dh];
        if (t == 2) {
          unsigned short tmp[4];
#pragma unroll
          for (int r = 0; r < 4; ++r) tmp[r] = f2bf(acc[mi][ni][r] + bias);
          *(uint2*)&Vtb[((size_t)h * DHD + dh) * S + mbase] = *(uint2*)tmp;
        } else {
          unsigned short* dst = (t == 0 ? Qb : Kb);
#pragma unroll
          for (int r = 0; r < 4; ++r) {
            float v = acc[mi][ni][r] + bias;
            if (t == 0) v *= ALPHA;
            dst[((size_t)h * S + mbase + r) * DHD + dh] = f2bf(v);
          }
        }
      } else {
#pragma unroll
        for (int r = 0; r < 4; ++r)
          outp[(size_t)(mbase + r) * DM + n] = acc[mi][ni][r] + b0[n];
      }
    }
}

// ---------------- flash attention: 32x32 MFMA, in-register P via cvt_pk + permlane32_swap ----------------
// grid (S/128, NH, KVSPLIT). 4 waves x 32 q-rows. KV tile 64, K/V dbuf in LDS (32KB).
// QK^T swapped: lane (l=lane&31, b=lane>>5) holds q=l, kv = t*32 + (reg&3)+8*(reg>>2)+4b.
// Softmax: in-lane tree + 1 shfl_xor(32). P->PV B-frag in-register:
// pair group g (regs 4g..4g+3) with group g+1, same word; permswap(lower, upper):
//   b=0 lane keeps own even-group words + receives partner's even-group words (vsrc.row0<-vdst.row1)
//   b=1 lane receives partner's odd-group words (vdst.row1<-vsrc.row0) + keeps own odd-group words
// -> B-frag words (d0,d1,s0,s1) = P[kv = ks*16 + b*8 + j][q], zero LDS traffic.
__global__ void __launch_bounds__(256, 2)
attn_kernel(const unsigned short* __restrict__ Qb, const unsigned short* __restrict__ Kb,
            const unsigned short* __restrict__ Vtb, unsigned short* __restrict__ accP,
            float2* __restrict__ lmP) {
  __shared__ unsigned short Ks[2][64 * 64];  // linear dest, XOR-swizzled content (pre-swizzled source)
  __shared__ unsigned short Vs[2][64 * 64];  // rows = dh of V^T
  const int tid = threadIdx.x;
  const int wid = tid >> 6, lane = tid & 63;
  const int l = lane & 31, b = lane >> 5;
  const int h = blockIdx.y, sp = blockIdx.z;
  const int q0 = blockIdx.x * 128;
  const int kvbase = sp * KVLEN;
  const unsigned short* Qh  = Qb  + (size_t)h * S * DHD;
  const unsigned short* Kh  = Kb  + (size_t)h * S * DHD;
  const unsigned short* Vth = Vtb + (size_t)h * DHD * S;
  const int qrow = q0 + wid * 32 + l;
  short8 qf[4];  // B-frag: col=q=l, k(dh) = ks*16 + b*8 + j
#pragma unroll
  for (int ks = 0; ks < 4; ++ks)
    qf[ks] = *(const short8*)&Qh[(size_t)qrow * DHD + ks * 16 + b * 8];

  float m_r = -__builtin_inff(), l_r = 0.f;
  f32x16 acc[2] = {};  // acc[dt]: rows dh = dt*32 + (reg&3)+8*(reg>>2)+4b, col q=l

  auto stage = [&](int bu, int kv0) {
#pragma unroll
    for (int i = 0; i < 2; ++i) {
      const int cb = (wid * 2 + i) * 64;
      const int c = cb + lane;
      const int r = c >> 3, up = c & 7;
      const int u = up ^ (r & 7);          // pre-swizzle global source (m173)
      async16(&Ks[bu][cb * 8], Kh  + (size_t)(kv0 + r) * DHD + u * 8);
      async16(&Vs[bu][cb * 8], Vth + (size_t)r * S + kv0 + u * 8);
    }
  };

  stage(0, kvbase);
  __syncthreads();
  int cur = 0;
  for (int kv0 = kvbase; kv0 < kvbase + KVLEN; kv0 += 64) {
    if (kv0 + 64 < kvbase + KVLEN) stage(cur ^ 1, kv0 + 64);
    // --- QK^T: sc[t] = sum_ks mfma32x32x16(K_frag, qf) ---
    f32x16 sc[2];
    __builtin_amdgcn_s_setprio(1);
#pragma unroll
    for (int t = 0; t < 2; ++t) {
      sc[t] = (f32x16)0.0f;
#pragma unroll
      for (int ks = 0; ks < 4; ++ks) {
        const int r = t * 32 + l;
        const int u = ks * 2 + b;
        const short8 kfr = *(const short8*)&Ks[cur][r * 64 + (u ^ (r & 7)) * 8];
        sc[t] = __builtin_amdgcn_mfma_f32_32x32x16_bf16(kfr, qf[ks], sc[t], 0, 0, 0);
      }
    }
    __builtin_amdgcn_s_setprio(0);
    // --- online softmax: 32 in-lane values + partner half via shfl_xor(32) ---
    float mx[16];
#pragma unroll
    for (int i = 0; i < 16; ++i) mx[i] = fmaxf(sc[0][i], sc[1][i]);
#pragma unroll
    for (int s2 = 8; s2 > 0; s2 >>= 1)
#pragma unroll
      for (int i = 0; i < 8; ++i) if (i < s2) mx[i] = fmaxf(mx[i], mx[i + s2]);
    float pm = mx[0];
    pm = fmaxf(pm, __shfl_xor(pm, 32));
    if (__any(pm > m_r + 8.f)) {  // defer-max (T13): rescale only when headroom exceeded
      const float mn = fmaxf(m_r, pm);
      const float sca = exp2f(m_r - mn);
      m_r = mn;
      l_r *= sca;
#pragma unroll
      for (int dt = 0; dt < 2; ++dt)
#pragma unroll
        for (int i = 0; i < 16; ++i) acc[dt][i] *= sca;
    }
#pragma unroll
    for (int t = 0; t < 2; ++t)
#pragma unroll
      for (int i = 0; i < 16; ++i) sc[t][i] = exp2f(sc[t][i] - m_r);  // p <= 2^8
    float sm[16];
#pragma unroll
    for (int i = 0; i < 16; ++i) sm[i] = sc[0][i] + sc[1][i];
#pragma unroll
    for (int s2 = 8; s2 > 0; s2 >>= 1)
#pragma unroll
      for (int i = 0; i < 8; ++i) if (i < s2) sm[i] += sm[i + s2];
    float ps = sm[0];
    ps += __shfl_xor(ps, 32);
    l_r += ps;
    // --- PV: P packed to bf16 in-register, halves exchanged via permlane32_swap ---
    __builtin_amdgcn_s_setprio(1);
#pragma unroll
    for (int t = 0; t < 2; ++t) {
      unsigned int pk[8];  // pk[2g], pk[2g+1] = words of reg-group g (kv = 8g+4b+{0..3})
#pragma unroll
      for (int i = 0; i < 8; ++i) pk[i] = cvt_pk_bf16(sc[t][2 * i], sc[t][2 * i + 1]);
#pragma unroll
      for (int kse = 0; kse < 2; ++kse) {
        // pair group 2kse (lower) with group 2kse+1 (upper), word-by-word
        unsigned int a0 = pk[4 * kse + 0], a1 = pk[4 * kse + 1];  // vdst = lower group
        unsigned int c0 = pk[4 * kse + 2], c1 = pk[4 * kse + 3];  // vsrc = upper group
        permswap(a0, c0);  // b=0: c0 <- partner lower; b=1: a0 <- partner upper
        permswap(a1, c1);
        uint4 pw = make_uint4(a0, a1, c0, c1);
        const short8 pb = *(const short8*)&pw;  // B-frag: col=q=l, k(kv)=ks*16+b*8+j
        const int ks = t * 2 + kse;
#pragma unroll
        for (int dt = 0; dt < 2; ++dt) {
          const int r2 = dt * 32 + l;
          const int u = ks * 2 + b;
          const short8 vf = *(const short8*)&Vs[cur][r2 * 64 + (u ^ (r2 & 7)) * 8];
          acc[dt] = __builtin_amdgcn_mfma_f32_32x32x16_bf16(vf, pb, acc[dt], 0, 0, 0);
        }
      }
    }
    __builtin_amdgcn_s_setprio(0);
    __syncthreads();  // waves done reading `cur`; prefetched loads drained (vmcnt before barrier)
    cur ^= 1;
  }
  // partial epilogue: raw acc (bf16) + (m,l); lane stores its 8 dh-quads for q=qrow
  const size_t prow = (size_t)(sp * NH + h) * S + qrow;
#pragma unroll
  for (int dt = 0; dt < 2; ++dt)
#pragma unroll
    for (int qd = 0; qd < 4; ++qd) {
      unsigned int w0 = cvt_pk_bf16(acc[dt][4 * qd + 0], acc[dt][4 * qd + 1]);
      unsigned int w1 = cvt_pk_bf16(acc[dt][4 * qd + 2], acc[dt][4 * qd + 3]);
      *(uint2*)&accP[prow * 64 + dt * 32 + qd * 8 + b * 4] = make_uint2(w0, w1);
    }
  if (b == 0) lmP[prow] = make_float2(m_r, l_r);
}

// ---------------- merge the KV-split partials -> concat bf16 ----------------
__global__ void merge_kernel(const unsigned short* __restrict__ accP, const float2* __restrict__ lmP,
                             unsigned short* __restrict__ concat) {
  const int c = blockIdx.x * 256 + threadIdx.x;  // one 8-wide dh chunk
  const int row = c >> 3;                        // h*S + q
  const int h = row >> 12, q = row & (S - 1);
  const int dh0 = (c & 7) * 8;
  const float2 lm0 = lmP[row];
  const float2 lm1 = lmP[NH * S + row];
  const float M = fmaxf(lm0.x, lm1.x);
  float w0 = exp2f(lm0.x - M), w1 = exp2f(lm1.x - M);
  const float inv = 1.f / (lm0.y * w0 + lm1.y * w1);
  w0 *= inv; w1 *= inv;
  const short8 v0 = *(const short8*)&accP[(size_t)row * 64 + dh0];
  const short8 v1 = *(const short8*)&accP[((size_t)NH * S + row) * 64 + dh0];
  unsigned short out[8];
#pragma unroll
  for (int j = 0; j < 8; ++j)
    out[j] = f2bf(bf2f((unsigned short)v0[j]) * w0 + bf2f((unsigned short)v1[j]) * w1);
  *(uint4*)&concat[(size_t)q * DM + h * DHD + dh0] = *(uint4*)out;
}

extern "C" void kernel_launch(void* const* d_in, const int* in_sizes, int n_in,
                              void* d_out, int out_size, void* d_ws, size_t ws_size,
                              hipStream_t stream) {
  const float* x  = (const float*)d_in[0];
  const float* Wq = (const float*)d_in[1];
  const float* Wk = (const float*)d_in[2];
  const float* Wv = (const float*)d_in[3];
  const float* bq = (const float*)d_in[4];
  const float* bk = (const float*)d_in[5];
  const float* bv = (const float*)d_in[6];
  const float* Wo = (const float*)d_in[7];
  const float* bo = (const float*)d_in[8];
  float* outp = (float*)d_out;
  char* ws = (char*)d_ws;
  // workspace carve (bytes); accP overlaps xb/Wcat (dead after gemm<0>)
  unsigned short* Qbuf   = (unsigned short*)(ws + 0);          // 4 MB [8][4096][64]
  unsigned short* Kbuf   = (unsigned short*)(ws + 4194304);    // 4 MB
  unsigned short* Vtbuf  = (unsigned short*)(ws + 8388608);    // 4 MB [8][64][4096]
  unsigned short* concat = (unsigned short*)(ws + 12582912);   // 4 MB [4096][512]
  unsigned short* Wob    = (unsigned short*)(ws + 16777216);   // 0.5 MB
  float2*         lmP    = (float2*)(ws + 17301504);           // 0.5 MB [2][8][4096]
  unsigned short* xb     = (unsigned short*)(ws + 17825792);   // 4 MB (dead after gemm<0>)
  unsigned short* Wcat   = (unsigned short*)(ws + 22020096);   // 1.5 MB (dead after gemm<0>)
  unsigned short* accP   = (unsigned short*)(ws + 17825792);   // 8 MB bf16 [2][8][4096][64]

  prep<<<NCVT + 192, 256, 0, stream>>>(x, xb, Wo, Wob, Wq, Wk, Wv, Wcat);
  gemm_bt<0><<<dim3(S / 128, 1536 / 64), 256, 0, stream>>>(xb, Wcat, DM, bq, bk, bv,
                                                           Qbuf, Kbuf, Vtbuf, nullptr);
  attn_kernel<<<dim3(S / 128, NH, KVSPLIT), 256, 0, stream>>>(Qbuf, Kbuf, Vtbuf, accP, lmP);
  merge_kernel<<<(NH * S * 8) / 256, 256, 0, stream>>>(accP, lmP, concat);
  gemm_bt<1><<<dim3(S / 128, DM / 64), 256, 0, stream>>>(concat, Wob, DM, bo, nullptr, nullptr,
                                                         nullptr, nullptr, nullptr, outp);
}

// Round 6
// 164.264 us; speedup vs baseline: 1.6122x; 1.0597x over previous
//
#include <hip/hip_runtime.h>

#define S 4096
#define DM 512
#define NH 8
#define DHD 64
#define ALPHA 0.18033688011112042f /* 0.125 * log2(e): folds attn scale + exp2 base into Q */

using short8 = __attribute__((ext_vector_type(8))) short;  // 8 bf16 (4 VGPRs)
using f32x4  = __attribute__((ext_vector_type(4))) float;
using f32x16 = __attribute__((ext_vector_type(16))) float; // 32x32 MFMA accumulator

__device__ __forceinline__ unsigned short f2bf(float f) {
  union { float f; unsigned int u; } v; v.f = f;
  unsigned int r = v.u + 0x7FFF + ((v.u >> 16) & 1);  // RNE
  return (unsigned short)(r >> 16);
}

__device__ __forceinline__ float bf2f(unsigned short u) {
  union { unsigned int u; float f; } v; v.u = (unsigned)u << 16;
  return v.f;
}

__device__ __forceinline__ unsigned int cvt_pk_bf16(float a, float b) {
  unsigned int r;
  asm("v_cvt_pk_bf16_f32 %0, %1, %2" : "=v"(r) : "v"(a), "v"(b));
  return r;  // low16 = bf16(a), high16 = bf16(b)
}

// v_permlane32_swap_b32 (verified R4->R5):
//   new vdst[lane+32] = old vsrc[lane]; new vsrc[lane] = old vdst[lane+32].
__device__ __forceinline__ void permswap(unsigned int& d, unsigned int& s) {
  asm("v_permlane32_swap_b32 %0, %1" : "+v"(d), "+v"(s));
}

__device__ __forceinline__ void async16(void* lds, const void* g) {
  // wave-uniform LDS base; HW writes base + lane*16
  __builtin_amdgcn_global_load_lds((const __attribute__((address_space(1))) void*)g,
                                   (__attribute__((address_space(3))) void*)lds, 16, 0, 0);
}

// ---------------- prep: fp32->bf16 (x, Wo) + Wq/Wk/Wv -> Wcat^T, one dispatch ----------------
#define NCVT ((S * DM + DM * DM) / 1024)  // 2304 blocks
__global__ void prep(const float* __restrict__ x, unsigned short* __restrict__ xb,
                     const float* __restrict__ Wo, unsigned short* __restrict__ Wob,
                     const float* __restrict__ Wq, const float* __restrict__ Wk,
                     const float* __restrict__ Wv, unsigned short* __restrict__ Wcat) {
  __shared__ float T[64][68];
  const int tid = threadIdx.x;
  if (blockIdx.x < NCVT) {  // block-uniform branch; no barrier in this path
    int i = (blockIdx.x * 256 + tid) * 4;
    const float* src; unsigned short* dst;
    if (i < S * DM) { src = x + i; dst = xb + i; }
    else { int j = i - S * DM; src = Wo + j; dst = Wob + j; }
    float4 v = *(const float4*)src;
    uint2 o;
    o.x = (unsigned)f2bf(v.x) | ((unsigned)f2bf(v.y) << 16);
    o.y = (unsigned)f2bf(v.z) | ((unsigned)f2bf(v.w) << 16);
    *(uint2*)dst = o;
    return;
  }
  const int bid = blockIdx.x - NCVT;
  const int d0 = (bid & 7) * 64, h = (bid >> 3) & 7, t = bid >> 6;
  const float* W = (t == 0 ? Wq : t == 1 ? Wk : Wv) + (size_t)h * DM * DHD;
#pragma unroll
  for (int i = 0; i < 4; ++i) {
    int c = i * 256 + tid;
    int r = c >> 4, u = c & 15;
    *(float4*)&T[r][u * 4] = *(const float4*)&W[(size_t)(d0 + r) * DHD + u * 4];
  }
  __syncthreads();
#pragma unroll
  for (int i = 0; i < 2; ++i) {
    int c = i * 256 + tid;
    int dh = c >> 3, u = c & 7;
    unsigned short tmp[8];
#pragma unroll
    for (int j = 0; j < 8; ++j) tmp[j] = f2bf(T[u * 8 + j][dh]);
    *(uint4*)&Wcat[((size_t)(t * 512) + h * 64 + dh) * DM + d0 + u * 8] = *(uint4*)tmp;
  }
}

// ---------------- 128x64-tile bt-GEMM for QKV (bias + Q-scale; V transposed to Vt) ----------------
__global__ void __launch_bounds__(256, 4)
gemm_qkv(const unsigned short* __restrict__ A,   // [M][512] bf16
         const unsigned short* __restrict__ B,   // [1536][512] bf16 (B^T rows)
         const float* __restrict__ b0, const float* __restrict__ b1, const float* __restrict__ b2,
         unsigned short* __restrict__ Qb, unsigned short* __restrict__ Kb, unsigned short* __restrict__ Vtb) {
  __shared__ unsigned short As[128 * 32];
  __shared__ unsigned short Bs[64 * 32];
  const int tid = threadIdx.x;
  const int wid = tid >> 6, lane = tid & 63;
  const int lo = lane & 15, hi = lane >> 4;
  const int wr = wid >> 1, wc = wid & 1;
  const int m0 = blockIdx.x * 128, n0 = blockIdx.y * 64;
  f32x4 acc[4][2] = {};
  for (int k0 = 0; k0 < DM; k0 += 32) {
    __syncthreads();
#pragma unroll
    for (int i = 0; i < 2; ++i) {
      const int cb = (wid * 2 + i) * 64;
      const int c = cb + lane, r = c >> 2, u = c & 3;
      async16(&As[cb * 8], A + (size_t)(m0 + r) * DM + k0 + u * 8);
    }
    {
      const int cb = wid * 64;
      const int c = cb + lane, r = c >> 2, u = c & 3;
      async16(&Bs[cb * 8], B + (size_t)(n0 + r) * DM + k0 + u * 8);
    }
    __syncthreads();
    short8 af[4], bfr[2];
#pragma unroll
    for (int m = 0; m < 4; ++m) af[m] = *(const short8*)&As[(wr * 64 + m * 16 + lo) * 32 + hi * 8];
#pragma unroll
    for (int n = 0; n < 2; ++n) bfr[n] = *(const short8*)&Bs[(wc * 32 + n * 16 + lo) * 32 + hi * 8];
#pragma unroll
    for (int m = 0; m < 4; ++m)
#pragma unroll
      for (int n = 0; n < 2; ++n)
        acc[m][n] = __builtin_amdgcn_mfma_f32_16x16x32_bf16(af[m], bfr[n], acc[m][n], 0, 0, 0);
  }
#pragma unroll
  for (int mi = 0; mi < 4; ++mi)
#pragma unroll
    for (int ni = 0; ni < 2; ++ni) {
      const int n = n0 + wc * 32 + ni * 16 + lo;
      const int mbase = m0 + wr * 64 + mi * 16 + hi * 4;
      const int t = n >> 9, h = (n >> 6) & 7, dh = n & 63;  // wave-uniform t,h per (mi,ni)
      const float bias = (t == 0 ? b0 : t == 1 ? b1 : b2)[h * 64 + dh];
      if (t == 2) {
        unsigned short tmp[4];
#pragma unroll
        for (int r = 0; r < 4; ++r) tmp[r] = f2bf(acc[mi][ni][r] + bias);
        *(uint2*)&Vtb[((size_t)h * DHD + dh) * S + mbase] = *(uint2*)tmp;
      } else {
        unsigned short* dst = (t == 0 ? Qb : Kb);
#pragma unroll
        for (int r = 0; r < 4; ++r) {
          float v = acc[mi][ni][r] + bias;
          if (t == 0) v *= ALPHA;
          dst[((size_t)h * S + mbase + r) * DHD + dh] = f2bf(v);
        }
      }
    }
}

// ---------------- 64x64-tile bt-GEMM for out-proj (fp32 out + bias) ----------------
// grid (S/64, DM/64) = 512 blocks -> 2 blocks/CU (vs 1/CU at 128-tile).
__global__ void __launch_bounds__(256, 4)
gemm_out(const unsigned short* __restrict__ A,   // [S][512] bf16 (concat)
         const unsigned short* __restrict__ B,   // [512][512] bf16 (Wo rows = B^T rows)
         const float* __restrict__ bias, float* __restrict__ outp) {
  __shared__ unsigned short As[64 * 32];
  __shared__ unsigned short Bs[64 * 32];
  const int tid = threadIdx.x;
  const int wid = tid >> 6, lane = tid & 63;
  const int lo = lane & 15, hi = lane >> 4;
  const int wr = wid >> 1, wc = wid & 1;
  const int m0 = blockIdx.x * 64, n0 = blockIdx.y * 64;
  f32x4 acc[2][2] = {};
  for (int k0 = 0; k0 < DM; k0 += 32) {
    __syncthreads();
    {
      const int c = wid * 64 + lane, r = c >> 2, u = c & 3;
      async16(&As[wid * 64 * 8], A + (size_t)(m0 + r) * DM + k0 + u * 8);
      async16(&Bs[wid * 64 * 8], B + (size_t)(n0 + r) * DM + k0 + u * 8);
    }
    __syncthreads();
    short8 af[2], bfr[2];
#pragma unroll
    for (int m = 0; m < 2; ++m) af[m] = *(const short8*)&As[(wr * 32 + m * 16 + lo) * 32 + hi * 8];
#pragma unroll
    for (int n = 0; n < 2; ++n) bfr[n] = *(const short8*)&Bs[(wc * 32 + n * 16 + lo) * 32 + hi * 8];
#pragma unroll
    for (int m = 0; m < 2; ++m)
#pragma unroll
      for (int n = 0; n < 2; ++n)
        acc[m][n] = __builtin_amdgcn_mfma_f32_16x16x32_bf16(af[m], bfr[n], acc[m][n], 0, 0, 0);
  }
#pragma unroll
  for (int mi = 0; mi < 2; ++mi)
#pragma unroll
    for (int ni = 0; ni < 2; ++ni) {
      const int n = n0 + wc * 32 + ni * 16 + lo;
      const int mbase = m0 + wr * 32 + mi * 16 + hi * 4;
#pragma unroll
      for (int r = 0; r < 4; ++r)
        outp[(size_t)(mbase + r) * DM + n] = acc[mi][ni][r] + bias[n];
    }
}

// ---------------- flash attention: 32x32 MFMA, in-register P, KV-split NSPLIT ----------------
// grid (S/128, NH, NSPLIT). 4 waves x 32 q-rows. KV tile 64, K/V dbuf in LDS (32KB -> 5 blocks/CU).
// Lane (l,b) holds q=l; kv = t*32 + (reg&3)+8*(reg>>2)+4b. Softmax in-lane + 1 shfl_xor(32).
// P->PV B-frag in-register via cvt_pk + permlane32_swap (R4-verified direction).
template <int NSPLIT>
__global__ void __launch_bounds__(256, 4)
attn_kernel(const unsigned short* __restrict__ Qb, const unsigned short* __restrict__ Kb,
            const unsigned short* __restrict__ Vtb, unsigned short* __restrict__ accP,
            float2* __restrict__ lmP) {
  constexpr int KVLEN = S / NSPLIT;
  __shared__ unsigned short Ks[2][64 * 64];  // linear dest, XOR-swizzled content (pre-swizzled source)
  __shared__ unsigned short Vs[2][64 * 64];  // rows = dh of V^T
  const int tid = threadIdx.x;
  const int wid = tid >> 6, lane = tid & 63;
  const int l = lane & 31, b = lane >> 5;
  const int h = blockIdx.y, sp = blockIdx.z;
  const int q0 = blockIdx.x * 128;
  const int kvbase = sp * KVLEN;
  const unsigned short* Qh  = Qb  + (size_t)h * S * DHD;
  const unsigned short* Kh  = Kb  + (size_t)h * S * DHD;
  const unsigned short* Vth = Vtb + (size_t)h * DHD * S;
  const int qrow = q0 + wid * 32 + l;
  short8 qf[4];  // B-frag: col=q=l, k(dh) = ks*16 + b*8 + j
#pragma unroll
  for (int ks = 0; ks < 4; ++ks)
    qf[ks] = *(const short8*)&Qh[(size_t)qrow * DHD + ks * 16 + b * 8];

  float m_r = -__builtin_inff(), l_r = 0.f;
  f32x16 acc[2] = {};  // acc[dt]: rows dh = dt*32 + (reg&3)+8*(reg>>2)+4b, col q=l

  auto stage = [&](int bu, int kv0) {
#pragma unroll
    for (int i = 0; i < 2; ++i) {
      const int cb = (wid * 2 + i) * 64;
      const int c = cb + lane;
      const int r = c >> 3, up = c & 7;
      const int u = up ^ (r & 7);          // pre-swizzle global source (m173)
      async16(&Ks[bu][cb * 8], Kh  + (size_t)(kv0 + r) * DHD + u * 8);
      async16(&Vs[bu][cb * 8], Vth + (size_t)r * S + kv0 + u * 8);
    }
  };

  stage(0, kvbase);
  __syncthreads();
  int cur = 0;
  for (int kv0 = kvbase; kv0 < kvbase + KVLEN; kv0 += 64) {
    if (kv0 + 64 < kvbase + KVLEN) stage(cur ^ 1, kv0 + 64);
    // --- QK^T: sc[t] = sum_ks mfma32x32x16(K_frag, qf) ---
    f32x16 sc[2];
    __builtin_amdgcn_s_setprio(1);
#pragma unroll
    for (int t = 0; t < 2; ++t) {
      sc[t] = (f32x16)0.0f;
#pragma unroll
      for (int ks = 0; ks < 4; ++ks) {
        const int r = t * 32 + l;
        const int u = ks * 2 + b;
        const short8 kfr = *(const short8*)&Ks[cur][r * 64 + (u ^ (r & 7)) * 8];
        sc[t] = __builtin_amdgcn_mfma_f32_32x32x16_bf16(kfr, qf[ks], sc[t], 0, 0, 0);
      }
    }
    __builtin_amdgcn_s_setprio(0);
    // --- online softmax: 32 in-lane values + partner half via shfl_xor(32) ---
    float mx[16];
#pragma unroll
    for (int i = 0; i < 16; ++i) mx[i] = fmaxf(sc[0][i], sc[1][i]);
#pragma unroll
    for (int s2 = 8; s2 > 0; s2 >>= 1)
#pragma unroll
      for (int i = 0; i < 8; ++i) if (i < s2) mx[i] = fmaxf(mx[i], mx[i + s2]);
    float pm = mx[0];
    pm = fmaxf(pm, __shfl_xor(pm, 32));
    if (__any(pm > m_r + 8.f)) {  // defer-max (T13): rescale only when headroom exceeded
      const float mn = fmaxf(m_r, pm);
      const float sca = exp2f(m_r - mn);
      m_r = mn;
      l_r *= sca;
#pragma unroll
      for (int dt = 0; dt < 2; ++dt)
#pragma unroll
        for (int i = 0; i < 16; ++i) acc[dt][i] *= sca;
    }
#pragma unroll
    for (int t = 0; t < 2; ++t)
#pragma unroll
      for (int i = 0; i < 16; ++i) sc[t][i] = exp2f(sc[t][i] - m_r);  // p <= 2^8
    float sm[16];
#pragma unroll
    for (int i = 0; i < 16; ++i) sm[i] = sc[0][i] + sc[1][i];
#pragma unroll
    for (int s2 = 8; s2 > 0; s2 >>= 1)
#pragma unroll
      for (int i = 0; i < 8; ++i) if (i < s2) sm[i] += sm[i + s2];
    float ps = sm[0];
    ps += __shfl_xor(ps, 32);
    l_r += ps;
    // --- PV: P packed to bf16 in-register, halves exchanged via permlane32_swap ---
    __builtin_amdgcn_s_setprio(1);
#pragma unroll
    for (int t = 0; t < 2; ++t) {
      unsigned int pk[8];  // pk[2g], pk[2g+1] = words of reg-group g (kv = 8g+4b+{0..3})
#pragma unroll
      for (int i = 0; i < 8; ++i) pk[i] = cvt_pk_bf16(sc[t][2 * i], sc[t][2 * i + 1]);
#pragma unroll
      for (int kse = 0; kse < 2; ++kse) {
        unsigned int a0 = pk[4 * kse + 0], a1 = pk[4 * kse + 1];  // vdst = lower group
        unsigned int c0 = pk[4 * kse + 2], c1 = pk[4 * kse + 3];  // vsrc = upper group
        permswap(a0, c0);
        permswap(a1, c1);
        uint4 pw = make_uint4(a0, a1, c0, c1);
        const short8 pb = *(const short8*)&pw;  // B-frag: col=q=l, k(kv)=ks*16+b*8+j
        const int ks = t * 2 + kse;
#pragma unroll
        for (int dt = 0; dt < 2; ++dt) {
          const int r2 = dt * 32 + l;
          const int u = ks * 2 + b;
          const short8 vf = *(const short8*)&Vs[cur][r2 * 64 + (u ^ (r2 & 7)) * 8];
          acc[dt] = __builtin_amdgcn_mfma_f32_32x32x16_bf16(vf, pb, acc[dt], 0, 0, 0);
        }
      }
    }
    __builtin_amdgcn_s_setprio(0);
    __syncthreads();  // waves done reading `cur`; prefetched loads drained (vmcnt before barrier)
    cur ^= 1;
  }
  // partial epilogue: raw acc (bf16) + (m,l); lane stores its 8 dh-quads for q=qrow
  const size_t prow = (size_t)(sp * NH + h) * S + qrow;
#pragma unroll
  for (int dt = 0; dt < 2; ++dt)
#pragma unroll
    for (int qd = 0; qd < 4; ++qd) {
      unsigned int w0 = cvt_pk_bf16(acc[dt][4 * qd + 0], acc[dt][4 * qd + 1]);
      unsigned int w1 = cvt_pk_bf16(acc[dt][4 * qd + 2], acc[dt][4 * qd + 3]);
      *(uint2*)&accP[prow * 64 + dt * 32 + qd * 8 + b * 4] = make_uint2(w0, w1);
    }
  if (b == 0) lmP[prow] = make_float2(m_r, l_r);
}

// ---------------- merge the KV-split partials -> concat bf16 ----------------
template <int NSPLIT>
__global__ void merge_kernel(const unsigned short* __restrict__ accP, const float2* __restrict__ lmP,
                             unsigned short* __restrict__ concat) {
  const int c = blockIdx.x * 256 + threadIdx.x;  // one 8-wide dh chunk
  const int row = c >> 3;                        // h*S + q
  const int h = row >> 12, q = row & (S - 1);
  const int dh0 = (c & 7) * 8;
  float2 lm[NSPLIT];
  float M = -__builtin_inff();
#pragma unroll
  for (int s = 0; s < NSPLIT; ++s) { lm[s] = lmP[(size_t)s * NH * S + row]; M = fmaxf(M, lm[s].x); }
  float w[NSPLIT], denom = 0.f;
#pragma unroll
  for (int s = 0; s < NSPLIT; ++s) { w[s] = exp2f(lm[s].x - M); denom += lm[s].y * w[s]; }
  const float inv = 1.f / denom;
  float o[8] = {};
#pragma unroll
  for (int s = 0; s < NSPLIT; ++s) {
    const short8 v = *(const short8*)&accP[((size_t)s * NH * S + row) * 64 + dh0];
#pragma unroll
    for (int j = 0; j < 8; ++j) o[j] += bf2f((unsigned short)v[j]) * w[s];
  }
  unsigned short out[8];
#pragma unroll
  for (int j = 0; j < 8; ++j) out[j] = f2bf(o[j] * inv);
  *(uint4*)&concat[(size_t)q * DM + h * DHD + dh0] = *(uint4*)out;
}

extern "C" void kernel_launch(void* const* d_in, const int* in_sizes, int n_in,
                              void* d_out, int out_size, void* d_ws, size_t ws_size,
                              hipStream_t stream) {
  const float* x  = (const float*)d_in[0];
  const float* Wq = (const float*)d_in[1];
  const float* Wk = (const float*)d_in[2];
  const float* Wv = (const float*)d_in[3];
  const float* bq = (const float*)d_in[4];
  const float* bk = (const float*)d_in[5];
  const float* bv = (const float*)d_in[6];
  const float* Wo = (const float*)d_in[7];
  const float* bo = (const float*)d_in[8];
  float* outp = (float*)d_out;
  char* ws = (char*)d_ws;
  // KVSPLIT=4 needs 35.1 MB of ws; fall back to the R5-proven split-2 layout otherwise.
  const int nsplit = (ws_size >= 35127296u) ? 4 : 2;
  // workspace carve (bytes); accP overlays xb/Wcat (dead after gemm_qkv)
  unsigned short* Qbuf   = (unsigned short*)(ws + 0);          // 4 MB [8][4096][64]
  unsigned short* Kbuf   = (unsigned short*)(ws + 4194304);    // 4 MB
  unsigned short* Vtbuf  = (unsigned short*)(ws + 8388608);    // 4 MB [8][64][4096]
  unsigned short* concat = (unsigned short*)(ws + 12582912);   // 4 MB [4096][512]
  unsigned short* Wob    = (unsigned short*)(ws + 16777216);   // 0.5 MB
  float2*         lmP    = (float2*)(ws + 17301504);           // nsplit*0.25 MB [nsplit][8][4096]
  const size_t xb_off    = 17301504 + (size_t)nsplit * NH * S * sizeof(float2);
  unsigned short* xb     = (unsigned short*)(ws + xb_off);     // 4 MB (dead after gemm_qkv)
  unsigned short* Wcat   = (unsigned short*)(ws + xb_off + 4194304);  // 1.5 MB (dead after gemm_qkv)
  unsigned short* accP   = (unsigned short*)(ws + xb_off);     // nsplit*4 MB bf16 [nsplit][8][4096][64]

  prep<<<NCVT + 192, 256, 0, stream>>>(x, xb, Wo, Wob, Wq, Wk, Wv, Wcat);
  gemm_qkv<<<dim3(S / 128, 1536 / 64), 256, 0, stream>>>(xb, Wcat, bq, bk, bv, Qbuf, Kbuf, Vtbuf);
  if (nsplit == 4) {
    attn_kernel<4><<<dim3(S / 128, NH, 4), 256, 0, stream>>>(Qbuf, Kbuf, Vtbuf, accP, lmP);
    merge_kernel<4><<<(NH * S * 8) / 256, 256, 0, stream>>>(accP, lmP, concat);
  } else {
    attn_kernel<2><<<dim3(S / 128, NH, 2), 256, 0, stream>>>(Qbuf, Kbuf, Vtbuf, accP, lmP);
    merge_kernel<2><<<(NH * S * 8) / 256, 256, 0, stream>>>(accP, lmP, concat);
  }
  gemm_out<<<dim3(S / 64, DM / 64), 256, 0, stream>>>(concat, Wob, bo, outp);
}